// Round 6
// baseline (290.734 us; speedup 1.0000x reference)
//
#include <hip/hip_runtime.h>
#include <stdint.h>

typedef unsigned int  u32;
typedef unsigned short u16;
typedef __bf16 v8bf __attribute__((ext_vector_type(8)));
typedef float  v4f  __attribute__((ext_vector_type(4)));

#define N_INST 256
#define BATCH  128
#define IN_DIM 1024
#define L_DIM  512
#define M_TOT  (N_INST*BATCH)   // 32768
#define NSLICE 16               // 16 colslices (64 pcols each), full K per block

// Fragment-tiled layouts (u16 units). Region = 1 KB = 64 lanes x 16 B.
// A (xb): region = mblk*256 + kt*16 + g*2 + kk   (g=row-group 0..7)
//   lane(q,c): row = mblk*128 + g*16 + c, k = kt*64 + kk*32 + q*8
// B (wpk): region = cs*128 + kt*8 + j*2 + kk     (cs=colslice 0..15, j=0..3)
//   lane(q,c): packed col p = cs*64 + j*16 + c, k = kt*64 + kk*32 + q*8
//   bcol = p>>4 = cs*4+j (even=V, odd=U), l = (bcol>>1)*16 + c
// ws: [0,64MB) xb; [64MB,66MB) wpk; [66MB,68MB) partial [16][M_TOT]
#define XB_BYTES   ((size_t)M_TOT * IN_DIM * 2)
#define WPK_BYTES  ((size_t)1024 * IN_DIM * 2)

__device__ inline u32 f2bf_pk(float a, float b){
  u32 ua = __builtin_bit_cast(u32, a);
  u32 ub = __builtin_bit_cast(u32, b);
  ua = (ua + 0x7FFFu + ((ua >> 16) & 1u)) >> 16;
  ub = (ub + 0x7FFFu + ((ub >> 16) & 1u)) & 0xFFFF0000u;
  return ua | ub;
}

#define PREP_XBLKS 16384
__global__ void prep(const float* __restrict__ x, const float* __restrict__ v,
                     const float* __restrict__ u, u16* __restrict__ xb,
                     u16* __restrict__ wpk){
  const int b = blockIdx.x;
  if (b < PREP_XBLKS){
    int t = b * 256 + threadIdx.x;
    int r = t >> 6, l = t & 63;
    int kk = r & 1, i = (r >> 1) & 3, h = (r >> 3) & 1, kt = (r >> 4) & 15, mb = r >> 8;
    int q = l >> 4, c = l & 15;
    int row = mb*128 + h*64 + i*16 + c;
    int k0  = kt*64 + kk*32 + q*8;
    const float* src = x + (size_t)row * IN_DIM + k0;
    float4 a0 = *reinterpret_cast<const float4*>(src);
    float4 a1 = *reinterpret_cast<const float4*>(src + 4);
    uint4 out;
    out.x = f2bf_pk(a0.x, a0.y); out.y = f2bf_pk(a0.z, a0.w);
    out.z = f2bf_pk(a1.x, a1.y); out.w = f2bf_pk(a1.z, a1.w);
    *reinterpret_cast<uint4*>(xb + (size_t)r*512 + l*8) = out;
  } else {
    int t = (b - PREP_XBLKS) * 256 + threadIdx.x;   // 131072 threads
    int r = t >> 6, l = t & 63;
    int kk = r & 1, j = (r >> 1) & 3, kt = (r >> 3) & 15, cs = r >> 7;
    int q = l >> 4, c = l & 15;
    int bcol = cs*4 + j;
    const float* src = (bcol & 1) ? u : v;
    int lcol = (bcol >> 1)*16 + c;
    int k0 = kt*64 + kk*32 + q*8;
    u32 o[4];
#pragma unroll
    for (int ii = 0; ii < 4; ++ii){
      float a  = src[(size_t)(k0 + 2*ii    ) * L_DIM + lcol];
      float bb = src[(size_t)(k0 + 2*ii + 1) * L_DIM + lcol];
      o[ii] = f2bf_pk(a, bb);
    }
    *reinterpret_cast<uint4*>(wpk + (size_t)r*512 + l*8) = make_uint4(o[0], o[1], o[2], o[3]);
  }
}

// ---- gemm_score: 256 rows x 64 pcols per block, BARRIER-FREE streaming ----
// Both A and B go global->reg (B-slice = 128 KB, L2-resident; wpk total 2 MB).
// No LDS, no __syncthreads in the K-loop -> no correlated all-wave stalls.
// af2/bf2: per-kk double buffers, refill-after-last-reader, distance = 2 kk-steps.
// Regs: af2 32 + bf2 32 + temps (VGPR ~110) + acc 64 AGPR -> <=170, 3 waves/SIMD.

#define LOADA2(KT, KK, P) { const u16* ak_ = awave + (size_t)(KT)*8192 + (KK)*512;    \
  _Pragma("unroll") for (int gi_ = 0; gi_ < 4; ++gi_)                                 \
    af2[P][gi_] = *reinterpret_cast<const v8bf*>(ak_ + gi_*1024); }

#define LOADB2(KT, KK, P) { const u16* bk_ = bwave + (size_t)((KT)*8 + (KK))*512;     \
  _Pragma("unroll") for (int j_ = 0; j_ < 4; ++j_)                                    \
    bf2[P][j_] = *reinterpret_cast<const v8bf*>(bk_ + j_*1024); }

// One kk-step on buffer P. If DO_R: refill bf2[P][j] right after j's last MFMA
// reader, and af2[P] after the whole cluster — both target step s+2.
#define STEP_S(P, DO_R, NKT, NKK) {                                                   \
  __builtin_amdgcn_s_setprio(1);                                                      \
  _Pragma("unroll") for (int j_ = 0; j_ < 4; ++j_){                                   \
    _Pragma("unroll") for (int gi_ = 0; gi_ < 4; ++gi_)                               \
      acc[gi_][j_] = __builtin_amdgcn_mfma_f32_16x16x32_bf16(                         \
          af2[P][gi_], bf2[P][j_], acc[gi_][j_], 0, 0, 0);                            \
    if (DO_R) bf2[P][j_] = *reinterpret_cast<const v8bf*>(                            \
        bwave + (size_t)((NKT)*8 + j_*2 + (NKK))*512);                                \
  }                                                                                   \
  __builtin_amdgcn_s_setprio(0);                                                      \
  if (DO_R) LOADA2(NKT, NKK, P); }

__launch_bounds__(256, 3)
__global__ void gemm_score(const u16* __restrict__ xb, const u16* __restrict__ wpk,
                           const float* __restrict__ w, float* __restrict__ partial){
  const int tid  = threadIdx.x;
  const u32 bid  = blockIdx.x;          // 0..2047
  const int xcd  = bid & 7;
  const int slot = bid >> 3;            // 0..255
  const int cs   = slot & 15;
  const int mr   = xcd*16 + (slot >> 4);  // 0..127, XCD-local A reuse
  const int mblk0= mr * 2;

  const int lane = tid & 63;
  const int wave = tid >> 6;
  const int q    = lane >> 4;
  const int c    = lane & 15;

  // wave -> mblk (wave>>1), row-groups g = (wave&1)*4 .. +3
  const u16* awave = xb + (size_t)(mblk0 + (wave>>1))*131072
                        + (size_t)((wave&1)*4)*1024 + lane*8;
  // B slice base for this cs (region = cs*128 + kt*8 + j*2 + kk)
  const u16* bwave = wpk + (size_t)cs*128*512 + lane*8;

  v8bf af2[2][4];
  v8bf bf2[2][4];
  v4f  acc[4][4];
#pragma unroll
  for (int gi = 0; gi < 4; ++gi)
#pragma unroll
    for (int j = 0; j < 4; ++j)
      acc[gi][j] = (v4f){0.f, 0.f, 0.f, 0.f};

  // prologue: buffers hold steps (kt=0,kk=0) and (kt=0,kk=1)
  LOADB2(0, 0, 0); LOADA2(0, 0, 0);
  LOADB2(0, 1, 1); LOADA2(0, 1, 1);

#pragma unroll 1
  for (int kt = 0; kt < 15; ++kt){
    STEP_S(0, 1, kt+1, 0);   // compute (kt,0); refill P0 <- (kt+1,0)  [distance 2]
    STEP_S(1, 1, kt+1, 1);   // compute (kt,1); refill P1 <- (kt+1,1)  [distance 2]
  }
  // tail kt=15: no refills
  STEP_S(0, 0, 0, 0);
  STEP_S(1, 0, 0, 0);

  // epilogue: j pairs (0,1)=V,U @ l=cs*32+c ; (2,3)=V,U @ +16
  const float wl0 = w[cs*32 + c];
  const float wl1 = w[cs*32 + 16 + c];
  float* pout = partial + (size_t)cs * M_TOT
              + (size_t)(mblk0 + (wave>>1))*128 + (wave&1)*64;

#pragma unroll
  for (int gi = 0; gi < 4; ++gi){
#pragma unroll
    for (int r = 0; r < 4; ++r){
      float t0 = 2.f / (1.f + __expf(-2.f * acc[gi][0][r])) - 1.f;
      float s0 = 1.f / (1.f + __expf(-acc[gi][1][r]));
      float t1 = 2.f / (1.f + __expf(-2.f * acc[gi][2][r])) - 1.f;
      float s1 = 1.f / (1.f + __expf(-acc[gi][3][r]));
      float v2 = t0*s0*wl0 + t1*s1*wl1;
      v2 += __shfl_xor(v2, 1, 64);
      v2 += __shfl_xor(v2, 2, 64);
      v2 += __shfl_xor(v2, 4, 64);
      v2 += __shfl_xor(v2, 8, 64);
      if (c == 0) pout[gi*16 + q*4 + r] = v2;   // slice-private rows
    }
  }
}

__global__ void softmax_inst(const float* __restrict__ partial, float* __restrict__ out){
  __shared__ float red[N_INST];
  const int b = blockIdx.x;
  const int n = threadIdx.x;
  float s = 0.f;
#pragma unroll
  for (int i = 0; i < NSLICE; ++i) s += partial[(size_t)i * M_TOT + n*BATCH + b];
  red[n] = s; __syncthreads();
  for (int st = N_INST/2; st > 0; st >>= 1){
    if (n < st) red[n] = fmaxf(red[n], red[n + st]);
    __syncthreads();
  }
  float mx = red[0]; __syncthreads();
  float e = __expf(s - mx);
  red[n] = e; __syncthreads();
  for (int st = N_INST/2; st > 0; st >>= 1){
    if (n < st) red[n] += red[n + st];
    __syncthreads();
  }
  out[n*BATCH + b] = e / red[0];
}

extern "C" void kernel_launch(void* const* d_in, const int* in_sizes, int n_in,
                              void* d_out, int out_size, void* d_ws, size_t ws_size,
                              hipStream_t stream) {
  const float* x = (const float*)d_in[0];
  const float* v = (const float*)d_in[1];
  const float* u = (const float*)d_in[2];
  const float* w = (const float*)d_in[3];
  u16*   xb      = (u16*)d_ws;
  u16*   wpk     = (u16*)((char*)d_ws + XB_BYTES);
  float* partial = (float*)((char*)d_ws + XB_BYTES + WPK_BYTES);
  float* out     = (float*)d_out;

  prep<<<dim3(PREP_XBLKS + 512), dim3(256), 0, stream>>>(x, v, u, xb, wpk);
  gemm_score<<<dim3(2048), dim3(256), 0, stream>>>(xb, wpk, w, partial);
  softmax_inst<<<dim3(BATCH), dim3(N_INST), 0, stream>>>(partial, out);
}